// Round 19
// baseline (468.352 us; speedup 1.0000x reference)
//
#include <hip/hip_runtime.h>
#include <math.h>
#include <stdint.h>

#define BATCH 8192
#define FEAT  64
#define HID   512
#define NS    4    // RK4 steps. absmax bit-exact 0.125 across NS=16..4.

typedef __attribute__((ext_vector_type(8))) short short8;
typedef __attribute__((ext_vector_type(4))) float f32x4;

__device__ inline unsigned short f2bf(float f) {
    union { float f; unsigned u; } v; v.f = f;
    unsigned r = v.u + 0x7fffu + ((v.u >> 16) & 1u);
    return (unsigned short)(r >> 16);
}
__device__ inline float bf2f(unsigned short h) {
    union { unsigned u; float f; } v; v.u = ((unsigned)h) << 16;
    return v.f;
}
__device__ inline float fast_tanh(float x) {
    float e = __expf(2.f * x);
    return 1.f - 2.f * __builtin_amdgcn_rcpf(e + 1.f);
}

// Swizzled LDS bf16 tile (row stride 1024B), 16B granules,
// phys_granule = granule ^ (row&7)  (G4 bank-conflict fix).
__device__ inline void sto_bf(unsigned short* base, int row, int col, unsigned short v) {
    *(unsigned short*)((char*)base + row * 1024 +
                       ((((col >> 3) ^ (row & 7))) << 4) + ((col & 7) << 1)) = v;
}
__device__ inline float ld_bf(const unsigned short* base, int row, int col) {
    return bf2f(*(const unsigned short*)((const char*)base + row * 1024 +
                 ((((col >> 3) ^ (row & 7))) << 4) + ((col & 7) << 1)));
}

// ---------------------------------------------------------------------------
// Core MFMA loop, software-pipelined: acc[2][NF] += A_lds @ Bpk^T.
// B-frags: 4-deep rotation via NONTEMPORAL loads — weights have ZERO L1 reuse
// (waves own disjoint columns; every line is an L1 miss), and the measured
// ~24 B/cyc/CU supply matches the L1 miss-tracking pool (~32 x 128B / 200cyc),
// not L1/L2 BW. `nt` bypasses L1 retention so misses queue on the deeper
// vmcnt/L2 path. L2 residency (multicast, round-15) is preserved: 1.15MB<<4MB.
// A-frags: 2-deep (LDS). NO k-rotation (round-15: krot cost 1.5x).
// ---------------------------------------------------------------------------
template<int KS, int KST, int NF, int RB>
__device__ inline void gemm_ab(const char* Al, const unsigned short* __restrict__ Bpk,
                               int cb0, int kb0, int lane, f32x4 acc[2][NF])
{
    const int l15 = lane & 15, l4 = lane >> 4;
    auto bload = [&](int ks, int nf) -> short8 {
        return __builtin_nontemporal_load((const short8*)(Bpk +
            ((size_t)((cb0 + nf) * KST + kb0 + ks) * 64 + lane) * 8));
    };
    auto aload = [&](int ks, int m) -> short8 {
        int row = m * 16 + l15;
        int g = (kb0 + ks) * 4 + l4;
        return *(const short8*)(Al + row * RB + ((g ^ (row & 7)) << 4));
    };

    short8 b0[NF], b1[NF], b2[NF], b3[NF], ac[2], an[2];
#pragma unroll
    for (int nf = 0; nf < NF; ++nf) b0[nf] = bload(0, nf);
    if (KS > 1) {
#pragma unroll
        for (int nf = 0; nf < NF; ++nf) b1[nf] = bload(1, nf);
    }
    if (KS > 2) {
#pragma unroll
        for (int nf = 0; nf < NF; ++nf) b2[nf] = bload(2, nf);
    }
    ac[0] = aload(0, 0); ac[1] = aload(0, 1);

#pragma unroll
    for (int ks = 0; ks < KS; ++ks) {
        if (ks + 1 < KS) { an[0] = aload(ks + 1, 0); an[1] = aload(ks + 1, 1); }
        if (ks + 3 < KS) {
#pragma unroll
            for (int nf = 0; nf < NF; ++nf) b3[nf] = bload(ks + 3, nf);
        }
#pragma unroll
        for (int m = 0; m < 2; ++m)
#pragma unroll
            for (int nf = 0; nf < NF; ++nf)
                acc[m][nf] = __builtin_amdgcn_mfma_f32_16x16x32_bf16(
                    ac[m], b0[nf], acc[m][nf], 0, 0, 0);
        if (ks + 1 < KS) {
#pragma unroll
            for (int nf = 0; nf < NF; ++nf) {
                b0[nf] = b1[nf]; b1[nf] = b2[nf]; b2[nf] = b3[nf];
            }
            ac[0] = an[0]; ac[1] = an[1];
        }
    }
}

// ---------------------------------------------------------------------------
// Fully fused dyn eval. One block = 32 batch rows, 1024 threads = 16 waves.
// STAGE 0..3 = RK4 stages; STAGE 3 applies RK4 combine + ld update, writing
// to Xdst/lddst (== d_out on the final step).
// Merged ph4: waves 0-3 dx GEMM, 4-7 g2 conversion, 8-15 F1. 5 barriers.
// ---------------------------------------------------------------------------
template<int STAGE>
__global__ __launch_bounds__(1024, 4) void ffjord_eval(
    const float* __restrict__ Xc, const float* __restrict__ Xm,
    const float* __restrict__ kin, float axc,
    const float* __restrict__ k1, const float* __restrict__ k2,
    const float* __restrict__ k3, float* __restrict__ kout,
    const unsigned short* __restrict__ W1Tpk, const float* __restrict__ b1,
    const float* __restrict__ w1t, float tval,
    const unsigned short* __restrict__ W2Tpk, const float* __restrict__ b2,
    const unsigned short* __restrict__ W2pk,
    const unsigned short* __restrict__ W3Tpk, const float* __restrict__ b3,
    const unsigned short* __restrict__ G3, const unsigned short* __restrict__ E1B,
    float* __restrict__ trout,
    const float* __restrict__ tr1, const float* __restrict__ tr2,
    const float* __restrict__ tr3, const float* __restrict__ ld, float h6,
    float* __restrict__ Xdst, float* __restrict__ lddst)
{
    __shared__ unsigned short h1s[32 * 512];   // h1, then F1=(1-h1^2)*E1
    __shared__ unsigned short h2s[32 * 512];   // h2
    __shared__ unsigned short g2s[32 * 512];   // g2 = g3*(1-h2^2)
    __shared__ unsigned short As[32 * 64];
    __shared__ float trp[16 * 32];

    const int tid = threadIdx.x, wid = tid >> 6, lane = tid & 63;
    const int l15 = lane & 15, l4 = lane >> 4;
    const int row0 = blockIdx.x * 32;

    // ---- phase 1: bf16(X + axc*kin) -> As (swizzled). 2 elems/thread ----
    {
        int row = tid >> 5, c0 = (tid & 31) * 2;
        size_t o = (size_t)(row0 + row) * 64 + c0;
        float v0 = Xc[o], v1 = Xc[o + 1];
        if constexpr (STAGE != 0) { v0 += axc * kin[o]; v1 += axc * kin[o + 1]; }
        unsigned pk = (unsigned)f2bf(v0) | ((unsigned)f2bf(v1) << 16);
        int g = c0 >> 3;
        *(unsigned*)((char*)As + row * 128 + ((g ^ (row & 7)) << 4) + ((c0 & 7) << 1)) = pk;
    }
    __syncthreads();

    // ---- phase 2: h1 = tanh(A @ W1[:64] + b1 + t*W1[64]) ----
    {
        f32x4 acc[2][2] = {};
        gemm_ab<2, 2, 2, 128>((const char*)As, W1Tpk, wid * 2, 0, lane, acc);
#pragma unroll
        for (int nf = 0; nf < 2; ++nf) {
            int col = wid * 32 + nf * 16 + l15;
            float bb = b1[col] + tval * w1t[col];
#pragma unroll
            for (int m = 0; m < 2; ++m)
#pragma unroll
                for (int r = 0; r < 4; ++r) {
                    int row = m * 16 + l4 * 4 + r;
                    sto_bf(h1s, row, col, f2bf(fast_tanh(acc[m][nf][r] + bb)));
                }
        }
    }
    __syncthreads();

    // ---- phase 3: h2 = tanh(h1 @ W2 + b2) ----
    {
        f32x4 acc[2][2] = {};
        gemm_ab<16, 16, 2, 1024>((const char*)h1s, W2Tpk, wid * 2, 0, lane, acc);
#pragma unroll
        for (int nf = 0; nf < 2; ++nf) {
            int col = wid * 32 + nf * 16 + l15;
            float bb = b2[col];
#pragma unroll
            for (int m = 0; m < 2; ++m)
#pragma unroll
                for (int r = 0; r < 4; ++r) {
                    int row = m * 16 + l4 * 4 + r;
                    sto_bf(h2s, row, col, f2bf(fast_tanh(acc[m][nf][r] + bb)));
                }
        }
    }
    __syncthreads();

    // ---- phase 4 (merged): waves 0-3: dx full-K GEMM -> global;
    //      waves 4-7: g2 = g3*(1-h2^2) -> g2s; waves 8-15: F1 in-place ----
    if (wid < 4) {
        f32x4 acc[2][1] = {};
        gemm_ab<16, 16, 1, 1024>((const char*)h2s, W3Tpk, wid, 0, lane, acc);
        int col = wid * 16 + l15;
        float bb = b3[col];
#pragma unroll
        for (int m = 0; m < 2; ++m)
#pragma unroll
            for (int r = 0; r < 4; ++r) {
                int row = m * 16 + l4 * 4 + r;
                size_t o = (size_t)(row0 + row) * 64 + col;
                float v = acc[m][0][r] + bb;
                if constexpr (STAGE < 3) kout[o] = v;
                else Xdst[o] = Xm[o] + h6 * (k1[o] + 2.f * k2[o] + 2.f * k3[o] + v);
            }
    } else if (wid < 8) {
        int tt = tid - 256;                  // 0..255
        int row = tt >> 3, cb = (tt & 7) * 64;
        size_t gb = (size_t)(row0 + row) * HID + cb;
#pragma unroll
        for (int q = 0; q < 8; ++q) {
            int c = cb + q * 8;
            short8 g3v = *(const short8*)(G3 + gb + q * 8);
            int goff = ((c >> 3) ^ (row & 7)) << 4;
            short8 hv = *(short8*)((char*)h2s + row * 1024 + goff);
            short8 f;
#pragma unroll
            for (int j = 0; j < 8; ++j) {
                float v = bf2f((unsigned short)hv[j]);
                f[j] = (short)f2bf(bf2f((unsigned short)g3v[j]) * (1.f - v * v));
            }
            *(short8*)((char*)g2s + row * 1024 + goff) = f;
        }
    } else {
        int tt = tid - 512;                  // 0..511
        int row = tt >> 4, cb = (tt & 15) * 32;
        size_t gb = (size_t)(row0 + row) * HID + cb;
        short8 e[4];
#pragma unroll
        for (int q = 0; q < 4; ++q) e[q] = *(const short8*)(E1B + gb + q * 8);
#pragma unroll
        for (int q = 0; q < 4; ++q) {
            int c = cb + q * 8;
            char* p = (char*)h1s + row * 1024 + ((((c >> 3) ^ (row & 7))) << 4);
            short8 hv = *(short8*)p;
            short8 f;
#pragma unroll
            for (int j = 0; j < 8; ++j) {
                float v = bf2f((unsigned short)hv[j]);
                f[j] = (short)f2bf((1.f - v * v) * bf2f((unsigned short)e[q][j]));
            }
            *(short8*)p = f;
        }
    }
    __syncthreads();

    // ---- phase 6: gt = g2 @ W2^T; tr partial = rowsum(gt * F1) ----
    {
        f32x4 acc[2][2] = {};
        gemm_ab<16, 16, 2, 1024>((const char*)g2s, W2pk, wid * 2, 0, lane, acc);
        float rs[2][4] = {{0.f, 0.f, 0.f, 0.f}, {0.f, 0.f, 0.f, 0.f}};
#pragma unroll
        for (int nf = 0; nf < 2; ++nf) {
            int col = wid * 32 + nf * 16 + l15;
#pragma unroll
            for (int m = 0; m < 2; ++m)
#pragma unroll
                for (int r = 0; r < 4; ++r) {
                    int row = m * 16 + l4 * 4 + r;
                    rs[m][r] += acc[m][nf][r] * ld_bf(h1s, row, col);
                }
        }
#pragma unroll
        for (int m = 0; m < 2; ++m)
#pragma unroll
            for (int r = 0; r < 4; ++r) {
                float v = rs[m][r];
                v += __shfl_xor(v, 1, 16);
                v += __shfl_xor(v, 2, 16);
                v += __shfl_xor(v, 4, 16);
                v += __shfl_xor(v, 8, 16);
                if (l15 == 0) trp[wid * 32 + m * 16 + l4 * 4 + r] = v;
            }
    }
    __syncthreads();

    if (tid < 32) {
        float s = 0.f;
#pragma unroll
        for (int w = 0; w < 16; ++w) s += trp[w * 32 + tid];
        if constexpr (STAGE < 3) {
            trout[row0 + tid] = s;
        } else {
            lddst[row0 + tid] = ld[row0 + tid] -
                h6 * (tr1[row0 + tid] + 2.f * tr2[row0 + tid] +
                      2.f * tr3[row0 + tid] + s);
        }
    }
}

// ---------------------------------------------------------------------------
// Weight pre-pack into MFMA B-fragment order (once per call).
// slot = (cb*KST + kb)*64 + lane;  n = cb*16 + (lane&15); k = kb*32 + (lane>>4)*8 + j
// Modes: 0 W1T (K=64), 1 W2T, 2 W2, 3 W3T (K=512), 4 W3 (K=64, for eps_prep).
// ---------------------------------------------------------------------------
__global__ __launch_bounds__(256) void pack_weights(
    const float* __restrict__ W1, const float* __restrict__ W2,
    const float* __restrict__ W3,
    unsigned short* __restrict__ W1Tpk, unsigned short* __restrict__ W2Tpk,
    unsigned short* __restrict__ W2pk, unsigned short* __restrict__ W3Tpk,
    unsigned short* __restrict__ W3pk)
{
    int s = blockIdx.x * 256 + threadIdx.x;   // 77824 slots
    unsigned short* dst; int KST, mode, base;
    if (s < 4096)       { dst = W1Tpk; KST = 2;  mode = 0; base = 0; }
    else if (s < 36864) { dst = W2Tpk; KST = 16; mode = 1; base = 4096; }
    else if (s < 69632) { dst = W2pk;  KST = 16; mode = 2; base = 36864; }
    else if (s < 73728) { dst = W3Tpk; KST = 16; mode = 3; base = 69632; }
    else                { dst = W3pk;  KST = 2;  mode = 4; base = 73728; }
    int ls = s - base;
    int l = ls & 63, t = ls >> 6;
    int kb = t % KST, cb = t / KST;
    int n = cb * 16 + (l & 15);
    int k0 = kb * 32 + (l >> 4) * 8;
    unsigned short v[8];
#pragma unroll
    for (int j = 0; j < 8; ++j) {
        int k = k0 + j;
        float f = (mode == 0) ? W1[(size_t)k * HID + n]
                : (mode == 1) ? W2[(size_t)k * HID + n]
                : (mode == 2) ? W2[(size_t)n * HID + k]
                : (mode == 3) ? W3[(size_t)k * FEAT + n]
                :               W3[(size_t)n * FEAT + k];
        v[j] = f2bf(f);
    }
    *(short8*)(dst + (size_t)ls * 8) = *(short8*)v;
}

// ---------------------------------------------------------------------------
// Fused prologue: g3 = eps @ W3^T and E1 = eps @ W1[:64] via MFMA;
// also X = x copy and ld = 0.
// ---------------------------------------------------------------------------
__global__ __launch_bounds__(1024, 4) void eps_prep(
    const float* __restrict__ eps, const float* __restrict__ x,
    float* __restrict__ X, float* __restrict__ ld,
    const unsigned short* __restrict__ W3pk, const unsigned short* __restrict__ W1Tpk,
    unsigned short* __restrict__ g3b, unsigned short* __restrict__ E1b)
{
    __shared__ unsigned short As[32 * 64];
    const int tid = threadIdx.x, wid = tid >> 6, lane = tid & 63;
    const int l15 = lane & 15, l4 = lane >> 4;
    const int row0 = blockIdx.x * 32;

    {
        int row = tid >> 5, c0 = (tid & 31) * 2;
        size_t o = (size_t)(row0 + row) * 64 + c0;
        float e0 = eps[o], e1 = eps[o + 1];
        unsigned pk = (unsigned)f2bf(e0) | ((unsigned)f2bf(e1) << 16);
        int g = c0 >> 3;
        *(unsigned*)((char*)As + row * 128 + ((g ^ (row & 7)) << 4) + ((c0 & 7) << 1)) = pk;
        X[o] = x[o]; X[o + 1] = x[o + 1];
        if (tid < 32) ld[row0 + tid] = 0.f;
    }
    __syncthreads();

    {   // g3 = eps @ W3^T
        f32x4 acc[2][2] = {};
        gemm_ab<2, 2, 2, 128>((const char*)As, W3pk, wid * 2, 0, lane, acc);
#pragma unroll
        for (int nf = 0; nf < 2; ++nf) {
            int col = wid * 32 + nf * 16 + l15;
#pragma unroll
            for (int m = 0; m < 2; ++m)
#pragma unroll
                for (int r = 0; r < 4; ++r) {
                    int row = m * 16 + l4 * 4 + r;
                    g3b[(size_t)(row0 + row) * HID + col] = f2bf(acc[m][nf][r]);
                }
        }
    }
    {   // E1 = eps @ W1[:64]
        f32x4 acc[2][2] = {};
        gemm_ab<2, 2, 2, 128>((const char*)As, W1Tpk, wid * 2, 0, lane, acc);
#pragma unroll
        for (int nf = 0; nf < 2; ++nf) {
            int col = wid * 32 + nf * 16 + l15;
#pragma unroll
            for (int m = 0; m < 2; ++m)
#pragma unroll
                for (int r = 0; r < 4; ++r) {
                    int row = m * 16 + l4 * 4 + r;
                    E1b[(size_t)(row0 + row) * HID + col] = f2bf(acc[m][nf][r]);
                }
        }
    }
}

// ---------------------------------------------------------------------------
extern "C" void kernel_launch(void* const* d_in, const int* in_sizes, int n_in,
                              void* d_out, int out_size, void* d_ws, size_t ws_size,
                              hipStream_t stream)
{
    const float* x   = (const float*)d_in[0];
    const float* eps = (const float*)d_in[1];
    const float* W1  = (const float*)d_in[2];
    const float* b1  = (const float*)d_in[3];
    const float* W2  = (const float*)d_in[4];
    const float* b2  = (const float*)d_in[5];
    const float* W3  = (const float*)d_in[6];
    const float* b3  = (const float*)d_in[7];
    (void)in_sizes; (void)n_in; (void)out_size; (void)ws_size;

    const size_t NZ = (size_t)BATCH * FEAT;
    float* out = (float*)d_out;

    float* ws = (float*)d_ws;
    size_t off = 0;
    auto alloc = [&](size_t n) { float* p = ws + off; off += n; return p; };

    float* X   = alloc(NZ);
    float* k1  = alloc(NZ);
    float* k2  = alloc(NZ);
    float* k3  = alloc(NZ);
    float* tr1 = alloc(BATCH);
    float* tr2 = alloc(BATCH);
    float* tr3 = alloc(BATCH);
    float* ld  = alloc(BATCH);

    unsigned short* bws = (unsigned short*)(ws + off);
    size_t boff = 0;
    auto balloc = [&](size_t n) { unsigned short* p = bws + boff; boff += n; return p; };
    unsigned short* g3b   = balloc((size_t)BATCH * HID);
    unsigned short* E1b   = balloc((size_t)BATCH * HID);
    unsigned short* W1Tpk = balloc((size_t)4096 * 8);
    unsigned short* W2Tpk = balloc((size_t)32768 * 8);
    unsigned short* W2pk  = balloc((size_t)32768 * 8);
    unsigned short* W3Tpk = balloc((size_t)4096 * 8);
    unsigned short* W3pk  = balloc((size_t)4096 * 8);

    // ---- prologue (2 launches) ----
    pack_weights<<<304, 256, 0, stream>>>(W1, W2, W3, W1Tpk, W2Tpk, W2pk, W3Tpk, W3pk);
    eps_prep<<<256, 1024, 0, stream>>>(eps, x, X, ld, W3pk, W1Tpk, g3b, E1b);

    const float h = 1.f / NS, h6 = h / 6.f;
    const float* w1t = W1 + (size_t)64 * HID;

    for (int s = 0; s < NS; ++s) {
        float t0 = s * h;
        bool last = (s == NS - 1);
        float* Xdst  = last ? out : X;
        float* lddst = last ? out + NZ : ld;
        ffjord_eval<0><<<256, 1024, 0, stream>>>(
            X, nullptr, nullptr, 0.f, nullptr, nullptr, nullptr, k1,
            W1Tpk, b1, w1t, t0, W2Tpk, b2, W2pk, W3Tpk, b3,
            g3b, E1b, tr1, nullptr, nullptr, nullptr, nullptr, h6,
            nullptr, nullptr);
        ffjord_eval<1><<<256, 1024, 0, stream>>>(
            X, nullptr, k1, 0.5f * h, nullptr, nullptr, nullptr, k2,
            W1Tpk, b1, w1t, t0 + 0.5f * h, W2Tpk, b2, W2pk, W3Tpk, b3,
            g3b, E1b, tr2, nullptr, nullptr, nullptr, nullptr, h6,
            nullptr, nullptr);
        ffjord_eval<2><<<256, 1024, 0, stream>>>(
            X, nullptr, k2, 0.5f * h, nullptr, nullptr, nullptr, k3,
            W1Tpk, b1, w1t, t0 + 0.5f * h, W2Tpk, b2, W2pk, W3Tpk, b3,
            g3b, E1b, tr3, nullptr, nullptr, nullptr, nullptr, h6,
            nullptr, nullptr);
        ffjord_eval<3><<<256, 1024, 0, stream>>>(
            X, X, k3, h, k1, k2, k3, nullptr,
            W1Tpk, b1, w1t, t0 + h, W2Tpk, b2, W2pk, W3Tpk, b3,
            g3b, E1b, nullptr, tr1, tr2, tr3, ld, h6,
            Xdst, lddst);
    }
}

// Round 20
// 326.435 us; speedup vs baseline: 1.4348x; 1.4348x over previous
//
#include <hip/hip_runtime.h>
#include <math.h>
#include <stdint.h>

#define BATCH 8192
#define FEAT  64
#define HID   512
#define NS    4    // RK4 steps. absmax bit-exact 0.125 across NS=16..4.

typedef __attribute__((ext_vector_type(8))) short short8;
typedef __attribute__((ext_vector_type(4))) float f32x4;

__device__ inline unsigned short f2bf(float f) {
    union { float f; unsigned u; } v; v.f = f;
    unsigned r = v.u + 0x7fffu + ((v.u >> 16) & 1u);
    return (unsigned short)(r >> 16);
}
__device__ inline float bf2f(unsigned short h) {
    union { unsigned u; float f; } v; v.u = ((unsigned)h) << 16;
    return v.f;
}
__device__ inline float fast_tanh(float x) {
    float e = __expf(2.f * x);
    return 1.f - 2.f * __builtin_amdgcn_rcpf(e + 1.f);
}

// Swizzled LDS bf16 tile (row stride 1024B), 16B granules,
// phys_granule = granule ^ (row&7)  (G4 bank-conflict fix).
__device__ inline void sto_bf(unsigned short* base, int row, int col, unsigned short v) {
    *(unsigned short*)((char*)base + row * 1024 +
                       ((((col >> 3) ^ (row & 7))) << 4) + ((col & 7) << 1)) = v;
}
__device__ inline float ld_bf(const unsigned short* base, int row, int col) {
    return bf2f(*(const unsigned short*)((const char*)base + row * 1024 +
                 ((((col >> 3) ^ (row & 7))) << 4) + ((col & 7) << 1)));
}

// ---------------------------------------------------------------------------
// Core MFMA loop, software-pipelined: acc[2][NF] += A_lds @ Bpk^T.
// B-frags: 4-deep rotation, PLAIN loads (round-19: nontemporal hint cost
// +43% — L1 retention serves cross-wave line reuse). A-frags: 2-deep (LDS).
// NO k-rotation (round-15: lockstep same-line requests are L2-multicast-
// served; krot cost 1.5x). Six structural perturbations refuted; this is
// the verified-optimal configuration.
// ---------------------------------------------------------------------------
template<int KS, int KST, int NF, int RB>
__device__ inline void gemm_ab(const char* Al, const unsigned short* __restrict__ Bpk,
                               int cb0, int kb0, int lane, f32x4 acc[2][NF])
{
    const int l15 = lane & 15, l4 = lane >> 4;
    auto bload = [&](int ks, int nf) -> short8 {
        return *(const short8*)(Bpk +
            ((size_t)((cb0 + nf) * KST + kb0 + ks) * 64 + lane) * 8);
    };
    auto aload = [&](int ks, int m) -> short8 {
        int row = m * 16 + l15;
        int g = (kb0 + ks) * 4 + l4;
        return *(const short8*)(Al + row * RB + ((g ^ (row & 7)) << 4));
    };

    short8 b0[NF], b1[NF], b2[NF], b3[NF], ac[2], an[2];
#pragma unroll
    for (int nf = 0; nf < NF; ++nf) b0[nf] = bload(0, nf);
    if (KS > 1) {
#pragma unroll
        for (int nf = 0; nf < NF; ++nf) b1[nf] = bload(1, nf);
    }
    if (KS > 2) {
#pragma unroll
        for (int nf = 0; nf < NF; ++nf) b2[nf] = bload(2, nf);
    }
    ac[0] = aload(0, 0); ac[1] = aload(0, 1);

#pragma unroll
    for (int ks = 0; ks < KS; ++ks) {
        if (ks + 1 < KS) { an[0] = aload(ks + 1, 0); an[1] = aload(ks + 1, 1); }
        if (ks + 3 < KS) {
#pragma unroll
            for (int nf = 0; nf < NF; ++nf) b3[nf] = bload(ks + 3, nf);
        }
#pragma unroll
        for (int m = 0; m < 2; ++m)
#pragma unroll
            for (int nf = 0; nf < NF; ++nf)
                acc[m][nf] = __builtin_amdgcn_mfma_f32_16x16x32_bf16(
                    ac[m], b0[nf], acc[m][nf], 0, 0, 0);
        if (ks + 1 < KS) {
#pragma unroll
            for (int nf = 0; nf < NF; ++nf) {
                b0[nf] = b1[nf]; b1[nf] = b2[nf]; b2[nf] = b3[nf];
            }
            ac[0] = an[0]; ac[1] = an[1];
        }
    }
}

// ---------------------------------------------------------------------------
// Fully fused dyn eval. One block = 32 batch rows, 1024 threads = 16 waves.
// STAGE 0..3 = RK4 stages; STAGE 3 applies RK4 combine + ld update, writing
// to Xdst/lddst (== d_out on the final step).
// Merged ph4: waves 0-3 dx GEMM, 4-7 g2 conversion, 8-15 F1. 5 barriers.
// ---------------------------------------------------------------------------
template<int STAGE>
__global__ __launch_bounds__(1024, 4) void ffjord_eval(
    const float* __restrict__ Xc, const float* __restrict__ Xm,
    const float* __restrict__ kin, float axc,
    const float* __restrict__ k1, const float* __restrict__ k2,
    const float* __restrict__ k3, float* __restrict__ kout,
    const unsigned short* __restrict__ W1Tpk, const float* __restrict__ b1,
    const float* __restrict__ w1t, float tval,
    const unsigned short* __restrict__ W2Tpk, const float* __restrict__ b2,
    const unsigned short* __restrict__ W2pk,
    const unsigned short* __restrict__ W3Tpk, const float* __restrict__ b3,
    const unsigned short* __restrict__ G3, const unsigned short* __restrict__ E1B,
    float* __restrict__ trout,
    const float* __restrict__ tr1, const float* __restrict__ tr2,
    const float* __restrict__ tr3, const float* __restrict__ ld, float h6,
    float* __restrict__ Xdst, float* __restrict__ lddst)
{
    __shared__ unsigned short h1s[32 * 512];   // h1, then F1=(1-h1^2)*E1
    __shared__ unsigned short h2s[32 * 512];   // h2
    __shared__ unsigned short g2s[32 * 512];   // g2 = g3*(1-h2^2)
    __shared__ unsigned short As[32 * 64];
    __shared__ float trp[16 * 32];

    const int tid = threadIdx.x, wid = tid >> 6, lane = tid & 63;
    const int l15 = lane & 15, l4 = lane >> 4;
    const int row0 = blockIdx.x * 32;

    // ---- phase 1: bf16(X + axc*kin) -> As (swizzled). 2 elems/thread ----
    {
        int row = tid >> 5, c0 = (tid & 31) * 2;
        size_t o = (size_t)(row0 + row) * 64 + c0;
        float v0 = Xc[o], v1 = Xc[o + 1];
        if constexpr (STAGE != 0) { v0 += axc * kin[o]; v1 += axc * kin[o + 1]; }
        unsigned pk = (unsigned)f2bf(v0) | ((unsigned)f2bf(v1) << 16);
        int g = c0 >> 3;
        *(unsigned*)((char*)As + row * 128 + ((g ^ (row & 7)) << 4) + ((c0 & 7) << 1)) = pk;
    }
    __syncthreads();

    // ---- phase 2: h1 = tanh(A @ W1[:64] + b1 + t*W1[64]) ----
    {
        f32x4 acc[2][2] = {};
        gemm_ab<2, 2, 2, 128>((const char*)As, W1Tpk, wid * 2, 0, lane, acc);
#pragma unroll
        for (int nf = 0; nf < 2; ++nf) {
            int col = wid * 32 + nf * 16 + l15;
            float bb = b1[col] + tval * w1t[col];
#pragma unroll
            for (int m = 0; m < 2; ++m)
#pragma unroll
                for (int r = 0; r < 4; ++r) {
                    int row = m * 16 + l4 * 4 + r;
                    sto_bf(h1s, row, col, f2bf(fast_tanh(acc[m][nf][r] + bb)));
                }
        }
    }
    __syncthreads();

    // ---- phase 3: h2 = tanh(h1 @ W2 + b2) ----
    {
        f32x4 acc[2][2] = {};
        gemm_ab<16, 16, 2, 1024>((const char*)h1s, W2Tpk, wid * 2, 0, lane, acc);
#pragma unroll
        for (int nf = 0; nf < 2; ++nf) {
            int col = wid * 32 + nf * 16 + l15;
            float bb = b2[col];
#pragma unroll
            for (int m = 0; m < 2; ++m)
#pragma unroll
                for (int r = 0; r < 4; ++r) {
                    int row = m * 16 + l4 * 4 + r;
                    sto_bf(h2s, row, col, f2bf(fast_tanh(acc[m][nf][r] + bb)));
                }
        }
    }
    __syncthreads();

    // ---- phase 4 (merged): waves 0-3: dx full-K GEMM -> global;
    //      waves 4-7: g2 = g3*(1-h2^2) -> g2s; waves 8-15: F1 in-place ----
    if (wid < 4) {
        f32x4 acc[2][1] = {};
        gemm_ab<16, 16, 1, 1024>((const char*)h2s, W3Tpk, wid, 0, lane, acc);
        int col = wid * 16 + l15;
        float bb = b3[col];
#pragma unroll
        for (int m = 0; m < 2; ++m)
#pragma unroll
            for (int r = 0; r < 4; ++r) {
                int row = m * 16 + l4 * 4 + r;
                size_t o = (size_t)(row0 + row) * 64 + col;
                float v = acc[m][0][r] + bb;
                if constexpr (STAGE < 3) kout[o] = v;
                else Xdst[o] = Xm[o] + h6 * (k1[o] + 2.f * k2[o] + 2.f * k3[o] + v);
            }
    } else if (wid < 8) {
        int tt = tid - 256;                  // 0..255
        int row = tt >> 3, cb = (tt & 7) * 64;
        size_t gb = (size_t)(row0 + row) * HID + cb;
#pragma unroll
        for (int q = 0; q < 8; ++q) {
            int c = cb + q * 8;
            short8 g3v = *(const short8*)(G3 + gb + q * 8);
            int goff = ((c >> 3) ^ (row & 7)) << 4;
            short8 hv = *(short8*)((char*)h2s + row * 1024 + goff);
            short8 f;
#pragma unroll
            for (int j = 0; j < 8; ++j) {
                float v = bf2f((unsigned short)hv[j]);
                f[j] = (short)f2bf(bf2f((unsigned short)g3v[j]) * (1.f - v * v));
            }
            *(short8*)((char*)g2s + row * 1024 + goff) = f;
        }
    } else {
        int tt = tid - 512;                  // 0..511
        int row = tt >> 4, cb = (tt & 15) * 32;
        size_t gb = (size_t)(row0 + row) * HID + cb;
        short8 e[4];
#pragma unroll
        for (int q = 0; q < 4; ++q) e[q] = *(const short8*)(E1B + gb + q * 8);
#pragma unroll
        for (int q = 0; q < 4; ++q) {
            int c = cb + q * 8;
            char* p = (char*)h1s + row * 1024 + ((((c >> 3) ^ (row & 7))) << 4);
            short8 hv = *(short8*)p;
            short8 f;
#pragma unroll
            for (int j = 0; j < 8; ++j) {
                float v = bf2f((unsigned short)hv[j]);
                f[j] = (short)f2bf((1.f - v * v) * bf2f((unsigned short)e[q][j]));
            }
            *(short8*)p = f;
        }
    }
    __syncthreads();

    // ---- phase 6: gt = g2 @ W2^T; tr partial = rowsum(gt * F1) ----
    {
        f32x4 acc[2][2] = {};
        gemm_ab<16, 16, 2, 1024>((const char*)g2s, W2pk, wid * 2, 0, lane, acc);
        float rs[2][4] = {{0.f, 0.f, 0.f, 0.f}, {0.f, 0.f, 0.f, 0.f}};
#pragma unroll
        for (int nf = 0; nf < 2; ++nf) {
            int col = wid * 32 + nf * 16 + l15;
#pragma unroll
            for (int m = 0; m < 2; ++m)
#pragma unroll
                for (int r = 0; r < 4; ++r) {
                    int row = m * 16 + l4 * 4 + r;
                    rs[m][r] += acc[m][nf][r] * ld_bf(h1s, row, col);
                }
        }
#pragma unroll
        for (int m = 0; m < 2; ++m)
#pragma unroll
            for (int r = 0; r < 4; ++r) {
                float v = rs[m][r];
                v += __shfl_xor(v, 1, 16);
                v += __shfl_xor(v, 2, 16);
                v += __shfl_xor(v, 4, 16);
                v += __shfl_xor(v, 8, 16);
                if (l15 == 0) trp[wid * 32 + m * 16 + l4 * 4 + r] = v;
            }
    }
    __syncthreads();

    if (tid < 32) {
        float s = 0.f;
#pragma unroll
        for (int w = 0; w < 16; ++w) s += trp[w * 32 + tid];
        if constexpr (STAGE < 3) {
            trout[row0 + tid] = s;
        } else {
            lddst[row0 + tid] = ld[row0 + tid] -
                h6 * (tr1[row0 + tid] + 2.f * tr2[row0 + tid] +
                      2.f * tr3[row0 + tid] + s);
        }
    }
}

// ---------------------------------------------------------------------------
// Weight pre-pack into MFMA B-fragment order (once per call).
// slot = (cb*KST + kb)*64 + lane;  n = cb*16 + (lane&15); k = kb*32 + (lane>>4)*8 + j
// Modes: 0 W1T (K=64), 1 W2T, 2 W2, 3 W3T (K=512), 4 W3 (K=64, for eps_prep).
// ---------------------------------------------------------------------------
__global__ __launch_bounds__(256) void pack_weights(
    const float* __restrict__ W1, const float* __restrict__ W2,
    const float* __restrict__ W3,
    unsigned short* __restrict__ W1Tpk, unsigned short* __restrict__ W2Tpk,
    unsigned short* __restrict__ W2pk, unsigned short* __restrict__ W3Tpk,
    unsigned short* __restrict__ W3pk)
{
    int s = blockIdx.x * 256 + threadIdx.x;   // 77824 slots
    unsigned short* dst; int KST, mode, base;
    if (s < 4096)       { dst = W1Tpk; KST = 2;  mode = 0; base = 0; }
    else if (s < 36864) { dst = W2Tpk; KST = 16; mode = 1; base = 4096; }
    else if (s < 69632) { dst = W2pk;  KST = 16; mode = 2; base = 36864; }
    else if (s < 73728) { dst = W3Tpk; KST = 16; mode = 3; base = 69632; }
    else                { dst = W3pk;  KST = 2;  mode = 4; base = 73728; }
    int ls = s - base;
    int l = ls & 63, t = ls >> 6;
    int kb = t % KST, cb = t / KST;
    int n = cb * 16 + (l & 15);
    int k0 = kb * 32 + (l >> 4) * 8;
    unsigned short v[8];
#pragma unroll
    for (int j = 0; j < 8; ++j) {
        int k = k0 + j;
        float f = (mode == 0) ? W1[(size_t)k * HID + n]
                : (mode == 1) ? W2[(size_t)k * HID + n]
                : (mode == 2) ? W2[(size_t)n * HID + k]
                : (mode == 3) ? W3[(size_t)k * FEAT + n]
                :               W3[(size_t)n * FEAT + k];
        v[j] = f2bf(f);
    }
    *(short8*)(dst + (size_t)ls * 8) = *(short8*)v;
}

// ---------------------------------------------------------------------------
// Fused prologue: g3 = eps @ W3^T and E1 = eps @ W1[:64] via MFMA;
// also X = x copy and ld = 0.
// ---------------------------------------------------------------------------
__global__ __launch_bounds__(1024, 4) void eps_prep(
    const float* __restrict__ eps, const float* __restrict__ x,
    float* __restrict__ X, float* __restrict__ ld,
    const unsigned short* __restrict__ W3pk, const unsigned short* __restrict__ W1Tpk,
    unsigned short* __restrict__ g3b, unsigned short* __restrict__ E1b)
{
    __shared__ unsigned short As[32 * 64];
    const int tid = threadIdx.x, wid = tid >> 6, lane = tid & 63;
    const int l15 = lane & 15, l4 = lane >> 4;
    const int row0 = blockIdx.x * 32;

    {
        int row = tid >> 5, c0 = (tid & 31) * 2;
        size_t o = (size_t)(row0 + row) * 64 + c0;
        float e0 = eps[o], e1 = eps[o + 1];
        unsigned pk = (unsigned)f2bf(e0) | ((unsigned)f2bf(e1) << 16);
        int g = c0 >> 3;
        *(unsigned*)((char*)As + row * 128 + ((g ^ (row & 7)) << 4) + ((c0 & 7) << 1)) = pk;
        X[o] = x[o]; X[o + 1] = x[o + 1];
        if (tid < 32) ld[row0 + tid] = 0.f;
    }
    __syncthreads();

    {   // g3 = eps @ W3^T
        f32x4 acc[2][2] = {};
        gemm_ab<2, 2, 2, 128>((const char*)As, W3pk, wid * 2, 0, lane, acc);
#pragma unroll
        for (int nf = 0; nf < 2; ++nf) {
            int col = wid * 32 + nf * 16 + l15;
#pragma unroll
            for (int m = 0; m < 2; ++m)
#pragma unroll
                for (int r = 0; r < 4; ++r) {
                    int row = m * 16 + l4 * 4 + r;
                    g3b[(size_t)(row0 + row) * HID + col] = f2bf(acc[m][nf][r]);
                }
        }
    }
    {   // E1 = eps @ W1[:64]
        f32x4 acc[2][2] = {};
        gemm_ab<2, 2, 2, 128>((const char*)As, W1Tpk, wid * 2, 0, lane, acc);
#pragma unroll
        for (int nf = 0; nf < 2; ++nf) {
            int col = wid * 32 + nf * 16 + l15;
#pragma unroll
            for (int m = 0; m < 2; ++m)
#pragma unroll
                for (int r = 0; r < 4; ++r) {
                    int row = m * 16 + l4 * 4 + r;
                    E1b[(size_t)(row0 + row) * HID + col] = f2bf(acc[m][nf][r]);
                }
        }
    }
}

// ---------------------------------------------------------------------------
extern "C" void kernel_launch(void* const* d_in, const int* in_sizes, int n_in,
                              void* d_out, int out_size, void* d_ws, size_t ws_size,
                              hipStream_t stream)
{
    const float* x   = (const float*)d_in[0];
    const float* eps = (const float*)d_in[1];
    const float* W1  = (const float*)d_in[2];
    const float* b1  = (const float*)d_in[3];
    const float* W2  = (const float*)d_in[4];
    const float* b2  = (const float*)d_in[5];
    const float* W3  = (const float*)d_in[6];
    const float* b3  = (const float*)d_in[7];
    (void)in_sizes; (void)n_in; (void)out_size; (void)ws_size;

    const size_t NZ = (size_t)BATCH * FEAT;
    float* out = (float*)d_out;

    float* ws = (float*)d_ws;
    size_t off = 0;
    auto alloc = [&](size_t n) { float* p = ws + off; off += n; return p; };

    float* X   = alloc(NZ);
    float* k1  = alloc(NZ);
    float* k2  = alloc(NZ);
    float* k3  = alloc(NZ);
    float* tr1 = alloc(BATCH);
    float* tr2 = alloc(BATCH);
    float* tr3 = alloc(BATCH);
    float* ld  = alloc(BATCH);

    unsigned short* bws = (unsigned short*)(ws + off);
    size_t boff = 0;
    auto balloc = [&](size_t n) { unsigned short* p = bws + boff; boff += n; return p; };
    unsigned short* g3b   = balloc((size_t)BATCH * HID);
    unsigned short* E1b   = balloc((size_t)BATCH * HID);
    unsigned short* W1Tpk = balloc((size_t)4096 * 8);
    unsigned short* W2Tpk = balloc((size_t)32768 * 8);
    unsigned short* W2pk  = balloc((size_t)32768 * 8);
    unsigned short* W3Tpk = balloc((size_t)4096 * 8);
    unsigned short* W3pk  = balloc((size_t)4096 * 8);

    // ---- prologue (2 launches) ----
    pack_weights<<<304, 256, 0, stream>>>(W1, W2, W3, W1Tpk, W2Tpk, W2pk, W3Tpk, W3pk);
    eps_prep<<<256, 1024, 0, stream>>>(eps, x, X, ld, W3pk, W1Tpk, g3b, E1b);

    const float h = 1.f / NS, h6 = h / 6.f;
    const float* w1t = W1 + (size_t)64 * HID;

    for (int s = 0; s < NS; ++s) {
        float t0 = s * h;
        bool last = (s == NS - 1);
        float* Xdst  = last ? out : X;
        float* lddst = last ? out + NZ : ld;
        ffjord_eval<0><<<256, 1024, 0, stream>>>(
            X, nullptr, nullptr, 0.f, nullptr, nullptr, nullptr, k1,
            W1Tpk, b1, w1t, t0, W2Tpk, b2, W2pk, W3Tpk, b3,
            g3b, E1b, tr1, nullptr, nullptr, nullptr, nullptr, h6,
            nullptr, nullptr);
        ffjord_eval<1><<<256, 1024, 0, stream>>>(
            X, nullptr, k1, 0.5f * h, nullptr, nullptr, nullptr, k2,
            W1Tpk, b1, w1t, t0 + 0.5f * h, W2Tpk, b2, W2pk, W3Tpk, b3,
            g3b, E1b, tr2, nullptr, nullptr, nullptr, nullptr, h6,
            nullptr, nullptr);
        ffjord_eval<2><<<256, 1024, 0, stream>>>(
            X, nullptr, k2, 0.5f * h, nullptr, nullptr, nullptr, k3,
            W1Tpk, b1, w1t, t0 + 0.5f * h, W2Tpk, b2, W2pk, W3Tpk, b3,
            g3b, E1b, tr3, nullptr, nullptr, nullptr, nullptr, h6,
            nullptr, nullptr);
        ffjord_eval<3><<<256, 1024, 0, stream>>>(
            X, X, k3, h, k1, k2, k3, nullptr,
            W1Tpk, b1, w1t, t0 + h, W2Tpk, b2, W2pk, W3Tpk, b3,
            g3b, E1b, nullptr, tr1, tr2, tr3, ld, h6,
            Xdst, lddst);
    }
}